// Round 4
// baseline (4880.622 us; speedup 1.0000x reference)
//
#include <hip/hip_runtime.h>
#include <hip/hip_bf16.h>

// DigitCaps routing, fused. Routing logits are linear in v:
//   b_k[b,r,c] = u_hat[b,r,c,:] . Vsum_k[b,c,:],  Vsum_k = v_1+...+v_{k-1}
// so no [B,R,C] state exists; u_hat lives only in registers.
//
// Round-3 post-mortem: passes stuck at 500us, VALU 6%, HBM 1%, VGPR 88-96.
// The wave-uniform W loads were lowered to scalar s_loads and serialized at
// ~750cyc each (SGPR pressure limits outstanding loads; compiler remat
// under the 256-VGPR cap doubled them). Round-4 fix: stage the W r-chunk in
// LDS (coalesced, once per pass) and read fragments via broadcast
// ds_read_b128; Vsum in lane-major uint4 bf16 LDS. 512-thr blocks.

#define NBATCH 512
#define NR     1152
#define NCLS   10
#define NOUT   16
#define RCHUNK 18          // r-rows per block; grid.x = 1152/18 = 64
#define NPX    64          // number of r-partials per batch-row
#define CO     160         // NCLS*NOUT

__device__ __forceinline__ unsigned short f2bf_rne(float x) {
    unsigned u = __float_as_uint(x);
    return (unsigned short)((u + 0x7fffu + ((u >> 16) & 1u)) >> 16);
}

template<bool FIRST>
__global__ __launch_bounds__(512, 2)
void caps_pass(const float* __restrict__ U, const float* __restrict__ W,
               const float* __restrict__ Vsum, float* __restrict__ Pg)
{
    __shared__ float wt[RCHUNK * 1280];          // 92160 B   W chunk, linear
    __shared__ float s_part[64][161];            // 41216 B   odd stride: 2-way = free
    __shared__ uint4 vs_sm[20 * 64];             // 20480 B   bf16 Vsum, lane-major

    const int tid  = threadIdx.x;
    const int lane = tid & 63;
    const int b0   = ((int)blockIdx.y) << 6;     // 64 batches per block, lane = batch
    const int rbase = (int)blockIdx.x * RCHUNK;

    // ---- stage W chunk: 18*1280 floats = 5760 float4, coalesced ----
    {
        const float4* Wg4 = reinterpret_cast<const float4*>(W + (size_t)rbase * 1280);
        float4* wt4 = reinterpret_cast<float4*>(wt);
        for (int k = tid; k < RCHUNK * 320; k += 512)
            wt4[k] = Wg4[k];
    }
    // ---- stage Vsum as packed bf16, lane-major [k=0..19][lane] ----
    if (!FIRST) {
        for (int f = tid; f < 20 * 64; f += 512) {
            const int k = f >> 6, l = f & 63;
            const float* vrow = Vsum + (size_t)(b0 + l) * CO + k * 8;
            float4 a = *reinterpret_cast<const float4*>(vrow);
            float4 b = *reinterpret_cast<const float4*>(vrow + 4);
            uint4 q;
            q.x = ((unsigned)f2bf_rne(a.y) << 16) | f2bf_rne(a.x);
            q.y = ((unsigned)f2bf_rne(a.w) << 16) | f2bf_rne(a.z);
            q.z = ((unsigned)f2bf_rne(b.y) << 16) | f2bf_rne(b.x);
            q.w = ((unsigned)f2bf_rne(b.w) << 16) | f2bf_rne(b.z);
            vs_sm[f] = q;
        }
    }
    for (int idx = tid; idx < 64 * 161; idx += 512)
        (&s_part[0][0])[idx] = 0.0f;
    __syncthreads();

    const int wv = __builtin_amdgcn_readfirstlane(tid >> 6);   // wave = r-offset
    const size_t ubase = (size_t)(b0 + lane) * (NR * 8);

    for (int rl = wv; rl < RCHUNK; rl += 8) {
        const int r = rbase + rl;
        const float4* up = reinterpret_cast<const float4*>(U + ubase + (size_t)r * 8);
        float4 u0 = up[0], u1 = up[1];
        const float uu[8] = {u0.x,u0.y,u0.z,u0.w, u1.x,u1.y,u1.z,u1.w};
        const float* wrow = wt + rl * 1280;      // wave-uniform LDS base

        float coef[NCLS];
        if (FIRST) {
            #pragma unroll
            for (int c = 0; c < NCLS; ++c) coef[c] = 0.1f;   // softmax of zeros
        } else {
            float lg[NCLS];
            #pragma unroll
            for (int c = 0; c < NCLS; ++c) {
                float uhc[NOUT];
                #pragma unroll
                for (int o = 0; o < NOUT; ++o) uhc[o] = 0.0f;
                #pragma unroll
                for (int i = 0; i < 8; ++i) {    // broadcast ds_read_b128 x4
                    const float4* wp = reinterpret_cast<const float4*>(wrow + c*128 + i*16);
                    float4 w0 = wp[0], w1 = wp[1], w2 = wp[2], w3 = wp[3];
                    const float wf[16] = {w0.x,w0.y,w0.z,w0.w, w1.x,w1.y,w1.z,w1.w,
                                          w2.x,w2.y,w2.z,w2.w, w3.x,w3.y,w3.z,w3.w};
                    const float ui = uu[i];
                    #pragma unroll
                    for (int o = 0; o < NOUT; ++o)
                        uhc[o] = __builtin_fmaf(ui, wf[o], uhc[o]);
                }
                // logit = uhc . Vsum[b][c][:]  (bf16 pairs, lane-major LDS)
                const uint4 qa = vs_sm[(c*2+0)*64 + lane];
                const uint4 qb = vs_sm[(c*2+1)*64 + lane];
                const unsigned pk[8] = {qa.x,qa.y,qa.z,qa.w, qb.x,qb.y,qb.z,qb.w};
                float acc = 0.0f;
                #pragma unroll
                for (int t = 0; t < 8; ++t) {
                    acc = __builtin_fmaf(uhc[t*2],   __uint_as_float(pk[t] << 16),        acc);
                    acc = __builtin_fmaf(uhc[t*2+1], __uint_as_float(pk[t] & 0xffff0000u), acc);
                }
                lg[c] = acc;
            }
            float mx = lg[0];
            #pragma unroll
            for (int c = 1; c < NCLS; ++c) mx = fmaxf(mx, lg[c]);
            float den = 0.0f;
            #pragma unroll
            for (int c = 0; c < NCLS; ++c) { float e = __expf(lg[c] - mx); coef[c] = e; den += e; }
            const float inv = 1.0f / den;
            #pragma unroll
            for (int c = 0; c < NCLS; ++c) coef[c] *= inv;
        }

        // accumulate s += coef * u_hat (recompute u_hat; rows lane-exclusive,
        // ds_add_f32 arbitrates across the 8 waves)
        #pragma unroll
        for (int c = 0; c < NCLS; ++c) {
            float uhc[NOUT];
            #pragma unroll
            for (int o = 0; o < NOUT; ++o) uhc[o] = 0.0f;
            #pragma unroll
            for (int i = 0; i < 8; ++i) {
                const float4* wp = reinterpret_cast<const float4*>(wrow + c*128 + i*16);
                float4 w0 = wp[0], w1 = wp[1], w2 = wp[2], w3 = wp[3];
                const float wf[16] = {w0.x,w0.y,w0.z,w0.w, w1.x,w1.y,w1.z,w1.w,
                                      w2.x,w2.y,w2.z,w2.w, w3.x,w3.y,w3.z,w3.w};
                const float ui = uu[i];
                #pragma unroll
                for (int o = 0; o < NOUT; ++o)
                    uhc[o] = __builtin_fmaf(ui, wf[o], uhc[o]);
            }
            const float cc = coef[c];
            #pragma unroll
            for (int o = 0; o < NOUT; ++o)
                atomicAdd(&s_part[lane][c * 16 + o], cc * uhc[o]);
        }
    }

    __syncthreads();

    // plain coalesced store of this block's partial: Pg[(y*NPX + x)][bl][m]
    float* pg = Pg + (size_t)((int)blockIdx.y * NPX + (int)blockIdx.x) * (64 * CO);
    for (int idx = tid; idx < 64 * CO; idx += 512) {
        int bl = idx / CO;
        int m  = idx - bl * CO;
        pg[idx] = s_part[bl][m];
    }
}

// Sums the 64 x-partials per (b,c,o), then squash. mode: 0 = write Vsum,
// 1 = Vsum += v, 2 = write final output.
__global__ __launch_bounds__(256)
void caps_reduce_squash(const float* __restrict__ Pg, float* __restrict__ Vsum,
                        float* __restrict__ out, const int mode)
{
    const int g = (int)blockIdx.x * 256 + threadIdx.x;   // [0, 81920), exact
    const int b = g / CO;
    const int m = g - b * CO;
    const int y = b >> 6, bl = b & 63;

    const float* p = Pg + ((size_t)(y * NPX) * 64 + bl) * CO + m;
    float s = 0.0f;
    #pragma unroll 16
    for (int x = 0; x < NPX; ++x)
        s += p[(size_t)x * (64 * CO)];

    // 16 lanes of one (b,c) are contiguous and 16-aligned within the wave
    float ss = s * s;
    ss += __shfl_xor(ss, 1);
    ss += __shfl_xor(ss, 2);
    ss += __shfl_xor(ss, 4);
    ss += __shfl_xor(ss, 8);
    const float f = sqrtf(ss) / (1.0f + ss);   // |s|/(1+|s|^2)
    const float v = f * s;

    if (mode == 2)      out[g] = v;
    else if (mode == 0) Vsum[g] = v;
    else                Vsum[g] += v;
}

extern "C" void kernel_launch(void* const* d_in, const int* in_sizes, int n_in,
                              void* d_out, int out_size, void* d_ws, size_t ws_size,
                              hipStream_t stream)
{
    (void)in_sizes; (void)n_in; (void)out_size; (void)ws_size;
    const float* U = (const float*)d_in[0];         // [512][1152][8] f32
    const float* W = (const float*)d_in[1];         // [1][1152][10][8][16] f32
    float* Pg   = (float*)d_ws;                     // [8][64][64][160] f32 = 21 MB
    float* Vsum = Pg + (size_t)NBATCH * NPX * CO;   // [512][10][16] f32
    float* out  = (float*)d_out;                    // [512][10][16] f32

    dim3 grid(NR / RCHUNK, NBATCH / 64);            // (64, 8) = 512 blocks
    dim3 blk(512);
    dim3 rgrid((NBATCH * CO) / 256);                // 320 blocks, exact

    caps_pass<true ><<<grid, blk, 0, stream>>>(U, W, nullptr, Pg);
    caps_reduce_squash<<<rgrid, 256, 0, stream>>>(Pg, Vsum, nullptr, 0);
    caps_pass<false><<<grid, blk, 0, stream>>>(U, W, Vsum, Pg);
    caps_reduce_squash<<<rgrid, 256, 0, stream>>>(Pg, Vsum, nullptr, 1);
    caps_pass<false><<<grid, blk, 0, stream>>>(U, W, Vsum, Pg);
    caps_reduce_squash<<<rgrid, 256, 0, stream>>>(Pg, Vsum, out, 2);
}

// Round 8
// 1605.023 us; speedup vs baseline: 3.0408x; 3.0408x over previous
//
#include <hip/hip_runtime.h>
#include <hip/hip_bf16.h>

// DigitCaps routing, fused. Routing logits are linear in v:
//   b_k[b,r,c] = u_hat[b,r,c,:] . Vsum_k[b,c,:],  Vsum_k = v_1+...+v_{k-1}
// so no [B,R,C] state is materialized.
//
// Round-4 post-mortem: 3 GB/pass WRITE_SIZE = scratch spill of the local
// float arrays in the LDS-broadcast inner loop. Round-5/6 fix: u_hat as 40
// NAMED float4 registers (macro-generated, zero arrays in the hot path),
// computed ONCE per r and pinned live across the softmax phase with empty
// asm. Round-6: fixed macro param 'w' colliding with float4 member .w.
// Rounds 6-7 never ran (GPU acquisition timeouts); resubmitting unchanged.

#define NBATCH 512
#define NR     1152
#define NCLS   10
#define NOUT   16
#define RCHUNK 18          // r-rows per block; grid.x = 1152/18 = 64
#define NPX    64          // number of r-partials per batch-row
#define CO     160         // NCLS*NOUT

__device__ __forceinline__ unsigned short f2bf_rne(float x) {
    unsigned u = __float_as_uint(x);
    return (unsigned short)((u + 0x7fffu + ((u >> 16) & 1u)) >> 16);
}

#define FOR_C(X) X(0) X(1) X(2) X(3) X(4) X(5) X(6) X(7) X(8) X(9)

#define DECLC(c) float4 uh##c##_0, uh##c##_1, uh##c##_2, uh##c##_3;

// NOTE: param names must not collide with float4 member names (x/y/z/w)!
#define FMA4(D, S, WV) \
    D.x = __builtin_fmaf(S, WV.x, D.x); \
    D.y = __builtin_fmaf(S, WV.y, D.y); \
    D.z = __builtin_fmaf(S, WV.z, D.z); \
    D.w = __builtin_fmaf(S, WV.w, D.w);

#define USTEP(c, k, UC) { \
    float4 wv0 = wp[(c)*32 + (k)*4 + 0]; \
    float4 wv1 = wp[(c)*32 + (k)*4 + 1]; \
    float4 wv2 = wp[(c)*32 + (k)*4 + 2]; \
    float4 wv3 = wp[(c)*32 + (k)*4 + 3]; \
    FMA4(A0, UC, wv0) FMA4(A1, UC, wv1) FMA4(A2, UC, wv2) FMA4(A3, UC, wv3) }

#define UHATC(c) { \
    float4 A0 = {0.f,0.f,0.f,0.f}, A1 = {0.f,0.f,0.f,0.f}; \
    float4 A2 = {0.f,0.f,0.f,0.f}, A3 = {0.f,0.f,0.f,0.f}; \
    USTEP(c,0,u0.x) USTEP(c,1,u0.y) USTEP(c,2,u0.z) USTEP(c,3,u0.w) \
    USTEP(c,4,u1.x) USTEP(c,5,u1.y) USTEP(c,6,u1.z) USTEP(c,7,u1.w) \
    uh##c##_0 = A0; uh##c##_1 = A1; uh##c##_2 = A2; uh##c##_3 = A3; }

// keep u_hat alive in VGPRs across the softmax phase (blocks remat/spill-DCE)
#define PINC(c) \
    asm volatile("" : "+v"(uh##c##_0.x), "+v"(uh##c##_0.y), "+v"(uh##c##_0.z), "+v"(uh##c##_0.w), \
                      "+v"(uh##c##_1.x), "+v"(uh##c##_1.y), "+v"(uh##c##_1.z), "+v"(uh##c##_1.w)); \
    asm volatile("" : "+v"(uh##c##_2.x), "+v"(uh##c##_2.y), "+v"(uh##c##_2.z), "+v"(uh##c##_2.w), \
                      "+v"(uh##c##_3.x), "+v"(uh##c##_3.y), "+v"(uh##c##_3.z), "+v"(uh##c##_3.w));

#define BFLO(Q) __uint_as_float((Q) << 16)
#define BFHI(Q) __uint_as_float((Q) & 0xffff0000u)

#define DOTP(ACC, FA, FB, Q) \
    ACC = __builtin_fmaf(FA.x, BFLO((Q).x), ACC); \
    ACC = __builtin_fmaf(FA.y, BFHI((Q).x), ACC); \
    ACC = __builtin_fmaf(FA.z, BFLO((Q).y), ACC); \
    ACC = __builtin_fmaf(FA.w, BFHI((Q).y), ACC); \
    ACC = __builtin_fmaf(FB.x, BFLO((Q).z), ACC); \
    ACC = __builtin_fmaf(FB.y, BFHI((Q).z), ACC); \
    ACC = __builtin_fmaf(FB.z, BFLO((Q).w), ACC); \
    ACC = __builtin_fmaf(FB.w, BFHI((Q).w), ACC);

#define LOGITC(c) { \
    uint4 qa = vs_sm[(2*(c))*64 + lane]; \
    uint4 qb = vs_sm[(2*(c)+1)*64 + lane]; \
    float acc = 0.0f; \
    DOTP(acc, uh##c##_0, uh##c##_1, qa) \
    DOTP(acc, uh##c##_2, uh##c##_3, qb) \
    lg[c] = acc; }

#define ACC4(c, AV, oo) \
    atomicAdd(&s_part[lane][(c)*16 + (oo) + 0], cc * AV.x); \
    atomicAdd(&s_part[lane][(c)*16 + (oo) + 1], cc * AV.y); \
    atomicAdd(&s_part[lane][(c)*16 + (oo) + 2], cc * AV.z); \
    atomicAdd(&s_part[lane][(c)*16 + (oo) + 3], cc * AV.w);

#define ACCC(c) { const float cc = coef[c]; \
    ACC4(c, uh##c##_0, 0) ACC4(c, uh##c##_1, 4) \
    ACC4(c, uh##c##_2, 8) ACC4(c, uh##c##_3, 12) }

// pass 1: coef uniform 0.1, fuse compute+accumulate per class (low pressure)
#define FUSED01(c) { \
    UHATC(c) const float cc = 0.1f; \
    ACC4(c, uh##c##_0, 0) ACC4(c, uh##c##_1, 4) \
    ACC4(c, uh##c##_2, 8) ACC4(c, uh##c##_3, 12) }

template<bool FIRST>
__global__ __launch_bounds__(512, 2)
void caps_pass(const float* __restrict__ U, const float* __restrict__ W,
               const float* __restrict__ Vsum, float* __restrict__ Pg)
{
    __shared__ float wt[RCHUNK * 1280];          // 92160 B  W chunk (f32, linear)
    __shared__ float s_part[64][161];            // 41216 B  odd stride: 2-way = free
    __shared__ uint4 vs_sm[20 * 64];             // 20480 B  bf16 Vsum, lane-major

    const int tid  = threadIdx.x;
    const int lane = tid & 63;
    const int b0   = ((int)blockIdx.y) << 6;     // 64 batches per block, lane = batch
    const int rbase = (int)blockIdx.x * RCHUNK;

    // ---- stage W chunk: 5760 float4, coalesced ----
    {
        const float4* Wg4 = reinterpret_cast<const float4*>(W + (size_t)rbase * 1280);
        float4* wt4 = reinterpret_cast<float4*>(wt);
        for (int k = tid; k < RCHUNK * 320; k += 512)
            wt4[k] = Wg4[k];
    }
    // ---- stage Vsum as packed bf16, lane-major [k=0..19][lane] ----
    if (!FIRST) {
        for (int f = tid; f < 20 * 64; f += 512) {
            const int k = f >> 6, l = f & 63;
            const float* vrow = Vsum + (size_t)(b0 + l) * CO + k * 8;
            float4 a = *reinterpret_cast<const float4*>(vrow);
            float4 b = *reinterpret_cast<const float4*>(vrow + 4);
            uint4 q;
            q.x = ((unsigned)f2bf_rne(a.y) << 16) | f2bf_rne(a.x);
            q.y = ((unsigned)f2bf_rne(a.w) << 16) | f2bf_rne(a.z);
            q.z = ((unsigned)f2bf_rne(b.y) << 16) | f2bf_rne(b.x);
            q.w = ((unsigned)f2bf_rne(b.w) << 16) | f2bf_rne(b.z);
            vs_sm[f] = q;
        }
    }
    for (int idx = tid; idx < 64 * 161; idx += 512)
        (&s_part[0][0])[idx] = 0.0f;
    __syncthreads();

    const int wv = __builtin_amdgcn_readfirstlane(tid >> 6);   // wave = r-offset
    const size_t ubase = (size_t)(b0 + lane) * (NR * 8);

    for (int rl = wv; rl < RCHUNK; rl += 8) {
        const float4* up = reinterpret_cast<const float4*>(U + ubase + (size_t)(rbase + rl) * 8);
        const float4 u0 = up[0], u1 = up[1];
        const float4* wp = reinterpret_cast<const float4*>(wt + rl * 1280);  // wave-uniform

        FOR_C(DECLC)

        if (FIRST) {
            FOR_C(FUSED01)
        } else {
            FOR_C(UHATC)
            FOR_C(PINC)

            float lg[NCLS];
            FOR_C(LOGITC)

            float mx = lg[0];
            #pragma unroll
            for (int c = 1; c < NCLS; ++c) mx = fmaxf(mx, lg[c]);
            float coef[NCLS];
            float den = 0.0f;
            #pragma unroll
            for (int c = 0; c < NCLS; ++c) { float e = __expf(lg[c] - mx); coef[c] = e; den += e; }
            const float inv = 1.0f / den;
            #pragma unroll
            for (int c = 0; c < NCLS; ++c) coef[c] *= inv;

            FOR_C(ACCC)
        }
    }

    __syncthreads();

    // plain coalesced store of this block's partial: Pg[(y*NPX + x)][bl][m]
    float* pg = Pg + (size_t)((int)blockIdx.y * NPX + (int)blockIdx.x) * (64 * CO);
    for (int idx = tid; idx < 64 * CO; idx += 512) {
        int bl = idx / CO;
        int m  = idx - bl * CO;
        pg[idx] = s_part[bl][m];
    }
}

// Sums the 64 x-partials per (b,c,o), then squash. mode: 0 = write Vsum,
// 1 = Vsum += v, 2 = write final output.
__global__ __launch_bounds__(256)
void caps_reduce_squash(const float* __restrict__ Pg, float* __restrict__ Vsum,
                        float* __restrict__ out, const int mode)
{
    const int g = (int)blockIdx.x * 256 + threadIdx.x;   // [0, 81920), exact
    const int b = g / CO;
    const int m = g - b * CO;
    const int y = b >> 6, bl = b & 63;

    const float* p = Pg + ((size_t)(y * NPX) * 64 + bl) * CO + m;
    float s = 0.0f;
    #pragma unroll 16
    for (int x = 0; x < NPX; ++x)
        s += p[(size_t)x * (64 * CO)];

    // 16 lanes of one (b,c) are contiguous and 16-aligned within the wave
    float ss = s * s;
    ss += __shfl_xor(ss, 1);
    ss += __shfl_xor(ss, 2);
    ss += __shfl_xor(ss, 4);
    ss += __shfl_xor(ss, 8);
    const float f = sqrtf(ss) / (1.0f + ss);   // |s|/(1+|s|^2)
    const float v = f * s;

    if (mode == 2)      out[g] = v;
    else if (mode == 0) Vsum[g] = v;
    else                Vsum[g] += v;
}

extern "C" void kernel_launch(void* const* d_in, const int* in_sizes, int n_in,
                              void* d_out, int out_size, void* d_ws, size_t ws_size,
                              hipStream_t stream)
{
    (void)in_sizes; (void)n_in; (void)out_size; (void)ws_size;
    const float* U = (const float*)d_in[0];         // [512][1152][8] f32
    const float* W = (const float*)d_in[1];         // [1][1152][10][8][16] f32
    float* Pg   = (float*)d_ws;                     // [8][64][64][160] f32 = 21 MB
    float* Vsum = Pg + (size_t)NBATCH * NPX * CO;   // [512][10][16] f32
    float* out  = (float*)d_out;                    // [512][10][16] f32

    dim3 grid(NR / RCHUNK, NBATCH / 64);            // (64, 8) = 512 blocks
    dim3 blk(512);
    dim3 rgrid((NBATCH * CO) / 256);                // 320 blocks, exact

    caps_pass<true ><<<grid, blk, 0, stream>>>(U, W, nullptr, Pg);
    caps_reduce_squash<<<rgrid, 256, 0, stream>>>(Pg, Vsum, nullptr, 0);
    caps_pass<false><<<grid, blk, 0, stream>>>(U, W, Vsum, Pg);
    caps_reduce_squash<<<rgrid, 256, 0, stream>>>(Pg, Vsum, nullptr, 1);
    caps_pass<false><<<grid, blk, 0, stream>>>(U, W, Vsum, Pg);
    caps_reduce_squash<<<rgrid, 256, 0, stream>>>(Pg, Vsum, out, 2);
}